// Round 12
// baseline (134.490 us; speedup 1.0000x reference)
//
#include <hip/hip_runtime.h>
#include <hip/hip_bf16.h>

typedef __attribute__((ext_vector_type(8))) short short8;
typedef __attribute__((ext_vector_type(4))) float f32x4;
typedef __attribute__((ext_vector_type(4))) int int4v;

#define DI __device__ __forceinline__

constexpr int Bq = 4, Cc = 512, Ss = 8192, Ee = 256;
constexpr int SP = 8448;   // padded s extent (128 + 8192 + 128)
constexpr long XSLAB = 4194304;  // xT slab elems (8192*512)

DI unsigned short f2bf(float f) {
    unsigned int u = __float_as_uint(f);
    unsigned int r = u + 0x7fffu + ((u >> 16) & 1u);
    return (unsigned short)(r >> 16);
}

union U16x8 { int4v v; unsigned short u[8]; };

DI void gll16(const void* g, void* l) {
    __builtin_amdgcn_global_load_lds(
        (const __attribute__((address_space(1))) unsigned int*)g,
        (__attribute__((address_space(3))) unsigned int*)l, 16, 0, 0);
}

DI unsigned pkbf(float lo, float hi) {
    unsigned r;
    asm("v_cvt_pk_bf16_f32 %0, %1, %2" : "=v"(r) : "v"(lo), "v"(hi));
    return r;
}

DI short8 mk8(unsigned a, unsigned b, unsigned c, unsigned d) {
    int4v v; v[0] = (int)a; v[1] = (int)b; v[2] = (int)c; v[3] = (int)d;
    union { int4v i; short8 s; } U; U.i = v; return U.s;
}

DI float gelu_t(float x) {
    float x2 = x * x;
    float z = x * (0.7978845608f + 0.0356774081f * x2);
    float az = fabsf(z);
    float e = __expf(-2.f * az);
    float th = (1.f - e) / (1.f + e);
    th = (z < 0.f) ? -th : th;
    return 0.5f * x * (1.f + th);
}

// sigma on 5-bit index k = [G1 G0 j2 j1 j0] -> [j2 G1 G0 j1 j0]; sigma^3 = id
DI int SIG(int k)  { return ((k & 4) << 2) | ((k & 24) >> 1) | (k & 3); }
DI int SIG2(int k) { return SIG(SIG(k)); }

// ---------- merged prep: x1 transpose (all 4 batches, xT in d_out scratch) +
//            weights->bf16 (Wo sigma-permuted) + zero pads of kTp/vp ----------
__global__ __launch_bounds__(256) void kpre(
    const float* __restrict__ x1,
    const float* __restrict__ Wq, const float* __restrict__ Wk, const float* __restrict__ Wv,
    const float* __restrict__ Wo, unsigned short* __restrict__ Wqkv_b, unsigned short* __restrict__ Wo_b,
    unsigned short* __restrict__ kTp, unsigned short* __restrict__ vp,
    unsigned short* __restrict__ xTo)
{
    int blk = blockIdx.x, t = threadIdx.x;
    if (blk < 4096) {
        int bb = blk >> 10, inner = blk & 1023;
        const float* x1b = x1 + (long)bb * Cc * Ss;
        unsigned short* xT = xTo + (long)bb * XSLAB;
        __shared__ unsigned short tile[64][72];
        int bs = inner & 127, bc = inner >> 7;
        int s0 = bs * 64, c0 = bc * 64;
        int cl = t >> 4, sl = (t & 15) * 4;
        for (int it = 0; it < 4; ++it) {
            int c = cl + it * 16;
            float4 vv = *(const float4*)(x1b + (long)(c0 + c) * Ss + s0 + sl);
            tile[c][sl + 0] = f2bf(vv.x);
            tile[c][sl + 1] = f2bf(vv.y);
            tile[c][sl + 2] = f2bf(vv.z);
            tile[c][sl + 3] = f2bf(vv.w);
        }
        __syncthreads();
        int s_loc = t >> 2, cseg = (t & 3) * 16;
        for (int half = 0; half < 2; ++half) {
            U16x8 u;
            for (int j = 0; j < 8; ++j) u.u[j] = tile[cseg + half * 8 + j][s_loc];
            *(int4v*)(xT + (long)(s0 + s_loc) * Cc + c0 + cseg + half * 8) = u.v;
        }
    } else if (blk < 5632) {
        int i = (blk - 4096) * 256 + t;
        if (i < 768 * 512) {
            int m = i >> 9, c = i & 511;
            const float* src = (m < 256) ? Wq : ((m < 512) ? Wk : Wv);
            Wqkv_b[i] = f2bf(src[(m & 255) * 512 + c]);
        }
        if (i < 512 * 256) {
            int kap = i & 255;
            int src = (i & ~255) | (kap & ~31) | SIG(kap & 31);
            Wo_b[i] = f2bf(Wo[src]);
        }
    } else {
        int i = (blk - 5632) * 256 + t;
        int4v z = {0, 0, 0, 0};
        if (i < 32768) {
            int b = i >> 13, r = i & 8191;
            int side = r >> 12, off = r & 4095;
            *(int4v*)(kTp + (long)b * SP * 256 + (long)(side ? 8320 : 0) * 256 + off * 8) = z;
        } else {
            int j = i - 32768;
            int b = j >> 13, r = j & 8191;
            int row = r >> 5, side = (r >> 4) & 1, sc = r & 15;
            *(int4v*)(vp + ((long)b * 256 + row) * SP + side * 8320 + sc * 8) = z;
        }
    }
}

// ---------- QKV GEMM: q,k -> [s][e], v -> [e][s] sigma-permuted cols; gll16 staging ----------
__global__ __launch_bounds__(256) void kqkv(
    const unsigned short* __restrict__ xT4, const unsigned short* __restrict__ Wqkv,
    const float* __restrict__ bq, const float* __restrict__ bk, const float* __restrict__ bv,
    unsigned short* __restrict__ qT, unsigned short* __restrict__ kTp, unsigned short* __restrict__ vp)
{
    __shared__ int4v As[1024], Bs[1024];
    int b = blockIdx.y;
    const unsigned short* xT = xT4 + (long)b * XSLAB;
    int wg = blockIdx.x;
    int type = wg >> 7, id = wg & 127;
    const unsigned short *A, *Bt; unsigned short* Op;
    long opitch; const float* bias; bool biasRow;
    if (type < 2) {
        int mt = id >> 1, nt = id & 1;
        A  = xT + (long)(mt * 128) * 512;
        Bt = Wqkv + (long)(type * 256 + nt * 128) * 512;
        if (type == 0)
            Op = qT + (long)b * Ss * Ee + (long)(mt * 128) * Ee + nt * 128;
        else
            Op = kTp + (long)b * SP * Ee + (long)(128 + mt * 128) * Ee + nt * 128;
        opitch = Ee;
        bias = (type ? bk : bq) + nt * 128;
        biasRow = false;
    } else {
        int mt = id >> 6, nt = id & 63;
        A  = Wqkv + (long)(512 + mt * 128) * 512;
        Bt = xT + (long)(nt * 128) * 512;
        Op = vp + (long)b * Ee * SP + (long)(mt * 128) * SP + 128 + nt * 128;
        opitch = SP;
        bias = bv + mt * 128;
        biasRow = true;
    }
    int t = threadIdx.x, lane = t & 63, wv = t >> 6;
    int wr = (wv >> 1) * 64, wc = (wv & 1) * 64;

    int soff[4];
    #pragma unroll
    for (int i = 0; i < 4; ++i) {
        int seg = t + 256 * i, row = seg >> 3, cs = seg & 7;
        soff[i] = row * 512 + ((cs ^ (row & 7)) * 8);
    }
    char* adst = (char*)As + wv * 1024;
    char* bdst = (char*)Bs + wv * 1024;

    f32x4 acc[4][4] = {};
    for (int kk = 0; kk < 8; ++kk) {
        #pragma unroll
        for (int i = 0; i < 4; ++i) {
            gll16(A  + soff[i] + kk * 64, adst + i * 4096);
            gll16(Bt + soff[i] + kk * 64, bdst + i * 4096);
        }
        asm volatile("s_waitcnt vmcnt(0)" ::: "memory");
        __syncthreads();
        for (int ks = 0; ks < 2; ++ks) {
            int csk = ks * 4 + (lane >> 4);
            short8 af[4], bfr[4];
            #pragma unroll
            for (int mi = 0; mi < 4; ++mi) {
                int m = wr + mi * 16 + (lane & 15);
                af[mi] = *(const short8*)&As[m * 8 + (csk ^ (m & 7))];
            }
            #pragma unroll
            for (int ni = 0; ni < 4; ++ni) {
                int nn = wc + ni * 16 + (lane & 15);
                bfr[ni] = *(const short8*)&Bs[nn * 8 + (csk ^ (nn & 7))];
            }
            #pragma unroll
            for (int mi = 0; mi < 4; ++mi)
                #pragma unroll
                for (int ni = 0; ni < 4; ++ni)
                    acc[mi][ni] = __builtin_amdgcn_mfma_f32_16x16x32_bf16(af[mi], bfr[ni], acc[mi][ni], 0, 0, 0);
        }
        __syncthreads();
    }
    for (int mi = 0; mi < 4; ++mi)
        for (int ni = 0; ni < 4; ++ni) {
            int mrow = wr + mi * 16 + ((lane >> 4) * 4);
            int ncol = wc + ni * 16 + (lane & 15);
            int nc2 = biasRow ? ((ncol & ~31) | SIG2(ncol & 31)) : ncol;
            for (int r = 0; r < 4; ++r) {
                float bval = biasRow ? bias[mrow + r] : bias[ncol];
                Op[(long)(mrow + r) * opitch + nc2] = f2bf(acc[mi][ni][r] + bval);
            }
        }
}

// ---------- fused attention + gelu + output projection (split-K) ----------
// grid 512 = (b,n,qq) XCD-swizzled; 8 waves: waves 0-3 keys [0,256), waves 4-7 keys [256,512)
// of the window; each wave 16 q rows; K chunk16 dbuf (counted vmcnt), V chunk32 single-buf;
// flash combine through LDS; projection split (q-tile x o-half) over all 8 waves.
__global__ __launch_bounds__(512, 2) void kattn(
    const unsigned short* __restrict__ qT, const unsigned short* __restrict__ kTp,
    const unsigned short* __restrict__ vp,  const unsigned short* __restrict__ Wo_b,
    const float* __restrict__ mask, const float* __restrict__ bo,
    float* __restrict__ y)
{
    // LDS: K [0,32K): half*16K + buf*8K | V [32K,64K): half*16K (single buf; also Wo dbuf + combine scratch)
    // fmask [64K,66K) | l2mask [66K,68K) (reused for m/l exchange) | bo [68K,70K)
    __shared__ __align__(16) char SH[71680];
    float* fmaskL  = (float*)(SH + 65536);
    float* l2maskL = (float*)(SH + 67584);
    float* boL     = (float*)(SH + 69632);

    int t = threadIdx.x, lane = t & 63, wv = t >> 6;
    int G = lane >> 4, l15 = lane & 15;
    int wq = wv & 3, half = wv >> 2;

    int phys = blockIdx.x;
    int L = (phys & 7) * 64 + (phys >> 3);          // bijective (512 % 8 == 0)
    int qq = L & 3, n = (L >> 2) & 31, b = L >> 7;
    int sqw = n * 256 + qq * 64 + wq * 16;

    // --- Q fragments (waves w and w+4 load the same rows; L2-hit)
    short8 qfrag[8];
    #pragma unroll
    for (int s = 0; s < 8; ++s)
        qfrag[s] = *(const short8*)(qT + ((long)b * Ss + sqw + l15) * 256 + 32 * s + 8 * G);

    // --- window masks + bias
    {
        int i = t;
        int sw = n * 256 - 128 + i;
        float f = 0.f;
        if (i != 511 && sw >= 0 && sw < Ss) f = mask[(long)b * Ss + sw];
        fmaskL[i] = f;
        l2maskL[i] = __log2f(f + 1e-6f);
    }
    if (t < 128) ((float4*)boL)[t] = ((const float4*)bo)[t];

    // --- staging pointers (pre-swizzled global, linear LDS dest)
    const unsigned short* ksrcp[2];
    #pragma unroll
    for (int i = 0; i < 2; ++i) {
        int krow = wq * 4 + i * 2 + (lane >> 5);   // LDS-local row in 16-row chunk
        ksrcp[i] = kTp + ((long)b * SP + n * 256 + half * 256 + krow) * 256
                 + (((lane & 31) ^ (krow & 7)) * 8);
    }
    const unsigned short* vsrcp[4];
    #pragma unroll
    for (int i = 0; i < 4; ++i) {
        int erow = wq * 64 + i * 16 + (lane >> 2);
        vsrcp[i] = vp + ((long)b * 256 + erow) * SP + n * 256 + half * 256
                 + (((lane & 3) ^ ((lane >> 2) & 3)) * 8);
    }
    const unsigned short* wsrcp[2];
    #pragma unroll
    for (int i = 0; i < 2; ++i) {
        int lr = wv * 4 + i * 2 + (lane >> 5);     // LDS-local row in 32-row Wo step
        long grow = (lr < 16) ? lr : (240 + lr);   // oh0: rows 16s+lr; oh1: 256+16s+(lr-16)
        wsrcp[i] = Wo_b + grow * 256 + (((lane & 31) ^ (lr & 7)) * 8);
    }

#define STAGE_K(C, BUF) {                                                     \
        char* kl = SH + half * 16384 + (BUF) * 8192 + wq * 2048;              \
        _Pragma("unroll")                                                     \
        for (int i = 0; i < 2; ++i) gll16(ksrcp[i] + (long)(C) * 4096, kl + i * 1024); }
#define STAGE_V(P) {                                                          \
        char* vl = SH + 32768 + half * 16384 + wq * 4096;                     \
        _Pragma("unroll")                                                     \
        for (int i = 0; i < 4; ++i) gll16(vsrcp[i] + (P) * 32, vl + i * 1024); }
#define WSTAGE(S, BUF) {                                                      \
        char* wl = SH + 32768 + (BUF) * 16384 + wv * 2048;                    \
        _Pragma("unroll")                                                     \
        for (int i = 0; i < 2; ++i) gll16(wsrcp[i] + (S) * 4096, wl + i * 1024); }

#define QKC(KB, EACC) {                                                       \
        __builtin_amdgcn_s_setprio(1);                                        \
        _Pragma("unroll")                                                     \
        for (int s_ = 0; s_ < 8; ++s_) {                                      \
            short8 kf_ = *(const short8*)((KB) + l15 * 512 + (((4 * s_ + G) ^ (l15 & 7)) * 16)); \
            EACC = __builtin_amdgcn_mfma_f32_16x16x32_bf16(kf_, qfrag[s_], EACC, 0, 0, 0); \
        }                                                                     \
        __builtin_amdgcn_s_setprio(0); }

#define SMAX(EACC, C, PC) {                                                   \
        int w0_ = half * 256 + (C) * 16;                                      \
        f32x4 lm_ = *(const f32x4*)&l2maskL[w0_ + 4 * G];                     \
        f32x4 fm_ = *(const f32x4*)&fmaskL[w0_ + 4 * G];                      \
        f32x4 ev_ = (EACC) * 0.09016844f + lm_;                               \
        float cm_ = fmaxf(fmaxf(ev_[0], ev_[1]), fmaxf(ev_[2], ev_[3]));      \
        cm_ = fmaxf(cm_, __shfl_xor(cm_, 16));                                \
        cm_ = fmaxf(cm_, __shfl_xor(cm_, 32));                                \
        if (__any(cm_ > mrun + 11.5416f)) {                                   \
            float mn_ = fmaxf(mrun, cm_); float sc_ = exp2f(mrun - mn_);      \
            mrun = mn_; lrun *= sc_;                                          \
            _Pragma("unroll")                                                 \
            for (int e_ = 0; e_ < 16; ++e_) oacc[e_] *= sc_;                  \
        }                                                                     \
        f32x4 p_;                                                             \
        p_[0] = exp2f(ev_[0] - mrun); p_[1] = exp2f(ev_[1] - mrun);           \
        p_[2] = exp2f(ev_[2] - mrun); p_[3] = exp2f(ev_[3] - mrun);           \
        float ss_ = (p_[0] + p_[1]) + (p_[2] + p_[3]);                        \
        ss_ += __shfl_xor(ss_, 16); ss_ += __shfl_xor(ss_, 32);               \
        lrun += ss_;                                                          \
        f32x4 pf_ = p_ * fm_;                                                 \
        PC[0] = pkbf(pf_[0], pf_[1]); PC[1] = pkbf(pf_[2], pf_[3]); }

    // prologue: K0->buf0, K1->buf1, V pair0
    STAGE_K(0, 0)
    STAGE_K(1, 1)
    STAGE_V(0)
    asm volatile("s_waitcnt vmcnt(0) lgkmcnt(0)" ::: "memory");
    __builtin_amdgcn_s_barrier();

    float mrun = -1e30f, lrun = 0.f;
    f32x4 oacc[16] = {};

    for (int p = 0; p < 8; ++p) {
        unsigned pcA[2], pcB[2];
        // ---- phase A: chunk 2p from K buf0
        {
            const char* KB = SH + half * 16384;
            f32x4 eacc = {};
            QKC(KB, eacc)
            SMAX(eacc, 2 * p, pcA)
        }
        asm volatile("s_waitcnt lgkmcnt(0)" ::: "memory");
        __builtin_amdgcn_s_barrier();
        if (p < 7) {
            STAGE_K(2 * p + 2, 0)
            asm volatile("s_waitcnt vmcnt(2)" ::: "memory");
        } else {
            asm volatile("s_waitcnt vmcnt(0)" ::: "memory");
        }
        __builtin_amdgcn_s_barrier();
        // ---- phase B: chunk 2p+1 from K buf1, then PV over the 32-key pair
        {
            const char* KB = SH + half * 16384 + 8192;
            f32x4 eacc = {};
            QKC(KB, eacc)
            SMAX(eacc, 2 * p + 1, pcB)
            const char* VB = SH + 32768 + half * 16384;
            short8 pf = mk8(pcA[0], pcA[1], pcB[0], pcB[1]);
            __builtin_amdgcn_s_setprio(1);
            #pragma unroll
            for (int et = 0; et < 16; ++et) {
                short8 vf = *(const short8*)(VB + (16 * et + l15) * 64 + ((G ^ (l15 & 3)) * 16));
                oacc[et] = __builtin_amdgcn_mfma_f32_16x16x32_bf16(vf, pf, oacc[et], 0, 0, 0);
            }
            __builtin_amdgcn_s_setprio(0);
        }
        asm volatile("s_waitcnt lgkmcnt(0)" ::: "memory");
        __builtin_amdgcn_s_barrier();
        if (p < 7) {
            STAGE_K(2 * p + 3, 1)
            STAGE_V(p + 1)
            asm volatile("s_waitcnt vmcnt(6)" ::: "memory");
        }
        __builtin_amdgcn_s_barrier();
    }

    // ---- flash combine: waves 4-7 partials -> waves 0-3 (two 32KB phases via V region)
    if (wv >= 4) {
        if (lane < 16) {
            l2maskL[wq * 32 + l15 * 2]     = mrun;
            l2maskL[wq * 32 + l15 * 2 + 1] = lrun;
        }
        #pragma unroll
        for (int et = 0; et < 8; ++et)
            *(f32x4*)(SH + 32768 + wq * 8192 + et * 1024 + lane * 16) = oacc[et];
    }
    asm volatile("s_waitcnt lgkmcnt(0)" ::: "memory");
    __builtin_amdgcn_s_barrier();

    float s1 = 1.f, s2 = 0.f, linv = 0.f;
    if (wv < 4) {
        float m2  = l2maskL[wq * 32 + l15 * 2];
        float l2v = l2maskL[wq * 32 + l15 * 2 + 1];
        float mm = fmaxf(mrun, m2);
        s1 = exp2f(mrun - mm);
        s2 = exp2f(m2 - mm);
        float ll = lrun * s1 + l2v * s2;
        linv = 1.f / ll;
        #pragma unroll
        for (int et = 0; et < 8; ++et) {
            f32x4 o2 = *(const f32x4*)(SH + 32768 + wq * 8192 + et * 1024 + lane * 16);
            oacc[et] = oacc[et] * s1 + o2 * s2;
        }
    }
    asm volatile("s_waitcnt lgkmcnt(0)" ::: "memory");
    __builtin_amdgcn_s_barrier();
    if (wv >= 4) {
        #pragma unroll
        for (int et = 8; et < 16; ++et)
            *(f32x4*)(SH + 32768 + wq * 8192 + (et - 8) * 1024 + lane * 16) = oacc[et];
    }
    asm volatile("s_waitcnt lgkmcnt(0)" ::: "memory");
    __builtin_amdgcn_s_barrier();
    if (wv < 4) {
        #pragma unroll
        for (int et = 8; et < 16; ++et) {
            f32x4 o2 = *(const f32x4*)(SH + 32768 + wq * 8192 + (et - 8) * 1024 + lane * 16);
            oacc[et] = oacc[et] * s1 + o2 * s2;
        }
        // gelu + pack h fragments, write to h region [0,32K) in frag layout
        #pragma unroll
        for (int s8 = 0; s8 < 8; ++s8) {
            f32x4 xa = oacc[2 * s8]     * linv;
            f32x4 xb = oacc[2 * s8 + 1] * linv;
            int4v hv;
            hv[0] = (int)pkbf(gelu_t(xa[0]), gelu_t(xa[1]));
            hv[1] = (int)pkbf(gelu_t(xa[2]), gelu_t(xa[3]));
            hv[2] = (int)pkbf(gelu_t(xb[0]), gelu_t(xb[1]));
            hv[3] = (int)pkbf(gelu_t(xb[2]), gelu_t(xb[3]));
            *(int4v*)(SH + wq * 8192 + s8 * 1024 + lane * 16) = hv;
        }
    }
    asm volatile("s_waitcnt lgkmcnt(0)" ::: "memory");
    __builtin_amdgcn_s_barrier();

    // ---- projection: wave = (q-tile wq, o-half half); h frags from LDS; Wo dbuf staged
    short8 hs[8];
    #pragma unroll
    for (int s8 = 0; s8 < 8; ++s8)
        hs[s8] = *(const short8*)(SH + wq * 8192 + s8 * 1024 + lane * 16);
    float ym = fmaskL[128 + qq * 64 + wq * 16 + l15];

    WSTAGE(0, 0)
    WSTAGE(1, 1)
    asm volatile("s_waitcnt vmcnt(2)" ::: "memory");
    __builtin_amdgcn_s_barrier();

    for (int step = 0; step < 16; ++step) {
        const char* WB = SH + 32768 + (step & 1) * 16384;
        f32x4 pacc = {};
        __builtin_amdgcn_s_setprio(1);
        #pragma unroll
        for (int s8 = 0; s8 < 8; ++s8) {
            short8 wf = *(const short8*)(WB + (half * 16 + l15) * 512 + (((4 * s8 + G) ^ (l15 & 7)) * 16));
            pacc = __builtin_amdgcn_mfma_f32_16x16x32_bf16(wf, hs[s8], pacc, 0, 0, 0);
        }
        __builtin_amdgcn_s_setprio(0);
        int o0 = half * 256 + 16 * step + 4 * G;
        f32x4 bo4 = *(const f32x4*)&boL[o0];
        #pragma unroll
        for (int r = 0; r < 4; ++r)
            y[((long)b * Cc + o0 + r) * Ss + sqw + l15] = (pacc[r] + bo4[r]) * ym;
        asm volatile("s_waitcnt lgkmcnt(0)" ::: "memory");
        __builtin_amdgcn_s_barrier();
        if (step < 14) {
            WSTAGE(step + 2, step & 1)
            asm volatile("s_waitcnt vmcnt(2)" ::: "memory");
        } else if (step == 14) {
            asm volatile("s_waitcnt vmcnt(0)" ::: "memory");
        }
        __builtin_amdgcn_s_barrier();
    }
#undef STAGE_K
#undef STAGE_V
#undef WSTAGE
#undef QKC
#undef SMAX
}

extern "C" void kernel_launch(void* const* d_in, const int* in_sizes, int n_in,
                              void* d_out, int out_size, void* d_ws, size_t ws_size,
                              hipStream_t stream)
{
    const float* x1   = (const float*)d_in[0];
    const float* mask = (const float*)d_in[1];
    const float* Wq   = (const float*)d_in[2];
    const float* bq   = (const float*)d_in[3];
    const float* Wk   = (const float*)d_in[4];
    const float* bk   = (const float*)d_in[5];
    const float* Wv   = (const float*)d_in[6];
    const float* bv   = (const float*)d_in[7];
    const float* Wo   = (const float*)d_in[8];
    const float* bo   = (const float*)d_in[9];
    float* y = (float*)d_out;

    // ws layout (bf16): Wqkv_b 786432 | Wo_b 262144 | qT 16777216 | kTp 17301504 | vp 17301504
    // xT (all 4 batches, 33.5MB) lives in d_out (64MB) and is overwritten by y at the end.
    if (ws_size < 52428800u) return;
    char* w = (char*)d_ws;
    unsigned short* Wqkv_b = (unsigned short*)(w);
    unsigned short* Wo_b   = (unsigned short*)(w + 786432);
    unsigned short* qT     = (unsigned short*)(w + 1048576);
    unsigned short* kTp    = (unsigned short*)(w + 17825792);
    unsigned short* vp     = (unsigned short*)(w + 35127296);
    unsigned short* xT4    = (unsigned short*)d_out;

    kpre<<<5888, 256, 0, stream>>>(x1, Wq, Wk, Wv, Wo, Wqkv_b, Wo_b, kTp, vp, xT4);
    kqkv<<<dim3(384, 4), 256, 0, stream>>>(xT4, Wqkv_b, bq, bk, bv, qT, kTp, vp);
    kattn<<<512, 512, 0, stream>>>(qT, kTp, vp, Wo_b, mask, bo, y);
}

// Round 13
// 114.358 us; speedup vs baseline: 1.1760x; 1.1760x over previous
//
#include <hip/hip_runtime.h>
#include <hip/hip_bf16.h>

typedef __attribute__((ext_vector_type(8))) short short8;
typedef __attribute__((ext_vector_type(4))) float f32x4;
typedef __attribute__((ext_vector_type(4))) int int4v;

#define DI __device__ __forceinline__

constexpr int Bq = 4, Cc = 512, Ss = 8192, Ee = 256;
constexpr int SP = 8448;   // padded s extent (128 + 8192 + 128)
constexpr long XSLAB = 4194304;  // xT slab elems (8192*512)

DI unsigned short f2bf(float f) {
    unsigned int u = __float_as_uint(f);
    unsigned int r = u + 0x7fffu + ((u >> 16) & 1u);
    return (unsigned short)(r >> 16);
}

union U16x8 { int4v v; unsigned short u[8]; };

DI void gll16(const void* g, void* l) {
    __builtin_amdgcn_global_load_lds(
        (const __attribute__((address_space(1))) unsigned int*)g,
        (__attribute__((address_space(3))) unsigned int*)l, 16, 0, 0);
}

DI unsigned pkbf(float lo, float hi) {
    unsigned r;
    asm("v_cvt_pk_bf16_f32 %0, %1, %2" : "=v"(r) : "v"(lo), "v"(hi));
    return r;
}

DI short8 mk8(unsigned a, unsigned b, unsigned c, unsigned d) {
    int4v v; v[0] = (int)a; v[1] = (int)b; v[2] = (int)c; v[3] = (int)d;
    union { int4v i; short8 s; } U; U.i = v; return U.s;
}

DI f32x4 max4(f32x4 a, f32x4 b) {
    f32x4 r;
    r[0] = fmaxf(a[0], b[0]); r[1] = fmaxf(a[1], b[1]);
    r[2] = fmaxf(a[2], b[2]); r[3] = fmaxf(a[3], b[3]);
    return r;
}

DI float gelu_t(float x) {
    float x2 = x * x;
    float z = x * (0.7978845608f + 0.0356774081f * x2);
    float az = fabsf(z);
    float e = __expf(-2.f * az);
    float th = (1.f - e) / (1.f + e);
    th = (z < 0.f) ? -th : th;
    return 0.5f * x * (1.f + th);
}

// sigma on 5-bit index k = [G1 G0 j2 j1 j0] -> [j2 G1 G0 j1 j0]; sigma^3 = id
DI int SIG(int k)  { return ((k & 4) << 2) | ((k & 24) >> 1) | (k & 3); }
DI int SIG2(int k) { return SIG(SIG(k)); }

// ---------- merged prep: x1 transpose (all 4 batches, xT in d_out scratch) +
//            weights->bf16 (Wo sigma-permuted) + zero pads of kTp/vp ----------
// grid 5888: [0,4096) transpose | [4096,5632) weights | [5632,5888) zero pads
__global__ __launch_bounds__(256) void kpre(
    const float* __restrict__ x1,
    const float* __restrict__ Wq, const float* __restrict__ Wk, const float* __restrict__ Wv,
    const float* __restrict__ Wo, unsigned short* __restrict__ Wqkv_b, unsigned short* __restrict__ Wo_b,
    unsigned short* __restrict__ kTp, unsigned short* __restrict__ vp,
    unsigned short* __restrict__ xTo)
{
    int blk = blockIdx.x, t = threadIdx.x;
    if (blk < 4096) {
        int bb = blk >> 10, inner = blk & 1023;
        const float* x1b = x1 + (long)bb * Cc * Ss;
        unsigned short* xT = xTo + (long)bb * XSLAB;
        __shared__ unsigned short tile[64][72];
        int bs = inner & 127, bc = inner >> 7;
        int s0 = bs * 64, c0 = bc * 64;
        int cl = t >> 4, sl = (t & 15) * 4;
        for (int it = 0; it < 4; ++it) {
            int c = cl + it * 16;
            float4 vv = *(const float4*)(x1b + (long)(c0 + c) * Ss + s0 + sl);
            tile[c][sl + 0] = f2bf(vv.x);
            tile[c][sl + 1] = f2bf(vv.y);
            tile[c][sl + 2] = f2bf(vv.z);
            tile[c][sl + 3] = f2bf(vv.w);
        }
        __syncthreads();
        int s_loc = t >> 2, cseg = (t & 3) * 16;
        for (int half = 0; half < 2; ++half) {
            U16x8 u;
            for (int j = 0; j < 8; ++j) u.u[j] = tile[cseg + half * 8 + j][s_loc];
            *(int4v*)(xT + (long)(s0 + s_loc) * Cc + c0 + cseg + half * 8) = u.v;
        }
    } else if (blk < 5632) {
        int i = (blk - 4096) * 256 + t;
        if (i < 768 * 512) {
            int m = i >> 9, c = i & 511;
            const float* src = (m < 256) ? Wq : ((m < 512) ? Wk : Wv);
            Wqkv_b[i] = f2bf(src[(m & 255) * 512 + c]);
        }
        if (i < 512 * 256) {
            int kap = i & 255;
            int src = (i & ~255) | (kap & ~31) | SIG(kap & 31);
            Wo_b[i] = f2bf(Wo[src]);
        }
    } else {
        int i = (blk - 5632) * 256 + t;   // 0..65535
        int4v z = {0, 0, 0, 0};
        if (i < 32768) {
            int b = i >> 13, r = i & 8191;
            int side = r >> 12, off = r & 4095;
            *(int4v*)(kTp + (long)b * SP * 256 + (long)(side ? 8320 : 0) * 256 + off * 8) = z;
        } else {
            int j = i - 32768;
            int b = j >> 13, r = j & 8191;
            int row = r >> 5, side = (r >> 4) & 1, sc = r & 15;
            *(int4v*)(vp + ((long)b * 256 + row) * SP + side * 8320 + sc * 8) = z;
        }
    }
}

// ---------- QKV GEMM: q,k -> [s][e], v -> [e][s] sigma-permuted cols; gll16 staging ----------
// grid (384, 4): blockIdx.y = batch; xT slab in d_out scratch.
__global__ __launch_bounds__(256) void kqkv(
    const unsigned short* __restrict__ xT4, const unsigned short* __restrict__ Wqkv,
    const float* __restrict__ bq, const float* __restrict__ bk, const float* __restrict__ bv,
    unsigned short* __restrict__ qT, unsigned short* __restrict__ kTp, unsigned short* __restrict__ vp)
{
    __shared__ int4v As[1024], Bs[1024];
    int b = blockIdx.y;
    const unsigned short* xT = xT4 + (long)b * XSLAB;
    int wg = blockIdx.x;
    int type = wg >> 7, id = wg & 127;     // 0=q 1=k 2=v
    const unsigned short *A, *Bt; unsigned short* Op;
    long opitch; const float* bias; bool biasRow;
    if (type < 2) {
        int mt = id >> 1, nt = id & 1;
        A  = xT + (long)(mt * 128) * 512;
        Bt = Wqkv + (long)(type * 256 + nt * 128) * 512;
        if (type == 0)
            Op = qT + (long)b * Ss * Ee + (long)(mt * 128) * Ee + nt * 128;
        else
            Op = kTp + (long)b * SP * Ee + (long)(128 + mt * 128) * Ee + nt * 128;
        opitch = Ee;
        bias = (type ? bk : bq) + nt * 128;
        biasRow = false;
    } else {
        int mt = id >> 6, nt = id & 63;
        A  = Wqkv + (long)(512 + mt * 128) * 512;
        Bt = xT + (long)(nt * 128) * 512;
        Op = vp + (long)b * Ee * SP + (long)(mt * 128) * SP + 128 + nt * 128;
        opitch = SP;
        bias = bv + mt * 128;
        biasRow = true;
    }
    int t = threadIdx.x, lane = t & 63, wv = t >> 6;
    int wr = (wv >> 1) * 64, wc = (wv & 1) * 64;

    int soff[4];
    #pragma unroll
    for (int i = 0; i < 4; ++i) {
        int seg = t + 256 * i, row = seg >> 3, cs = seg & 7;
        soff[i] = row * 512 + ((cs ^ (row & 7)) * 8);
    }
    char* adst = (char*)As + wv * 1024;
    char* bdst = (char*)Bs + wv * 1024;

    f32x4 acc[4][4] = {};
    for (int kk = 0; kk < 8; ++kk) {
        #pragma unroll
        for (int i = 0; i < 4; ++i) {
            gll16(A  + soff[i] + kk * 64, adst + i * 4096);
            gll16(Bt + soff[i] + kk * 64, bdst + i * 4096);
        }
        asm volatile("s_waitcnt vmcnt(0)" ::: "memory");
        __syncthreads();
        for (int ks = 0; ks < 2; ++ks) {
            int csk = ks * 4 + (lane >> 4);
            short8 af[4], bfr[4];
            #pragma unroll
            for (int mi = 0; mi < 4; ++mi) {
                int m = wr + mi * 16 + (lane & 15);
                af[mi] = *(const short8*)&As[m * 8 + (csk ^ (m & 7))];
            }
            #pragma unroll
            for (int ni = 0; ni < 4; ++ni) {
                int nn = wc + ni * 16 + (lane & 15);
                bfr[ni] = *(const short8*)&Bs[nn * 8 + (csk ^ (nn & 7))];
            }
            #pragma unroll
            for (int mi = 0; mi < 4; ++mi)
                #pragma unroll
                for (int ni = 0; ni < 4; ++ni)
                    acc[mi][ni] = __builtin_amdgcn_mfma_f32_16x16x32_bf16(af[mi], bfr[ni], acc[mi][ni], 0, 0, 0);
        }
        __syncthreads();
    }
    for (int mi = 0; mi < 4; ++mi)
        for (int ni = 0; ni < 4; ++ni) {
            int mrow = wr + mi * 16 + ((lane >> 4) * 4);
            int ncol = wc + ni * 16 + (lane & 15);
            int nc2 = biasRow ? ((ncol & ~31) | SIG2(ncol & 31)) : ncol;
            for (int r = 0; r < 4; ++r) {
                float bval = biasRow ? bias[mrow + r] : bias[ncol];
                Op[(long)(mrow + r) * opitch + nc2] = f2bf(acc[mi][ni][r] + bval);
            }
        }
}

// ---------- fused attention + gelu + output projection (round-6-measured schedule) ----------
// grid 256 = (b,n,qhalf) XCD-paired; 8 waves x 16 q rows; chunk 64; natural-log softmax.
__global__ __launch_bounds__(512, 1) void kattn(
    const unsigned short* __restrict__ qT, const unsigned short* __restrict__ kTp,
    const unsigned short* __restrict__ vp,  const unsigned short* __restrict__ Wo_b,
    const float* __restrict__ mask, const float* __restrict__ bo,
    float* __restrict__ y)
{
    __shared__ __align__(16) char SH[137216];
    float* fmaskL = (float*)(SH + 131072);
    float* lmaskL = (float*)(SH + 133120);
    float* boL    = (float*)(SH + 135168);

    int t = threadIdx.x, lane = t & 63, wv = t >> 6;   // wv in [0,8)
    int G = lane >> 4, l15 = lane & 15;

    int phys = blockIdx.x;
    int xx = phys & 7, kk2 = phys >> 3;
    int L = ((xx + 8 * (kk2 >> 1)) << 1) | (kk2 & 1);
    int qh = L & 1, n = (L >> 1) & 31, b = L >> 6;
    int sqw = n * 256 + qh * 128 + wv * 16;

    short8 qfrag[8];
    #pragma unroll
    for (int s = 0; s < 8; ++s)
        qfrag[s] = *(const short8*)(qT + ((long)b * Ss + sqw + l15) * 256 + 32 * s + 8 * G);

    {
        int i = t;
        int sw = n * 256 - 128 + i;
        float f = 0.f;
        if (i != 511 && sw >= 0 && sw < Ss) f = mask[(long)b * Ss + sw];
        fmaskL[i] = f;
        lmaskL[i] = __logf(f + 1e-6f);
    }
    if (t < 128) ((float4*)boL)[t] = ((const float4*)bo)[t];

    const unsigned short* ksrcp[4];
    const unsigned short* vsrcp[4];
    #pragma unroll
    for (int i = 0; i < 4; ++i) {
        int krow = wv * 8 + i * 2 + (lane >> 5);
        ksrcp[i] = kTp + ((long)b * SP + n * 256 + krow) * 256 + (((lane & 31) ^ (krow & 7)) * 8);
        int erow = wv * 32 + i * 8 + (lane >> 3);
        vsrcp[i] = vp + ((long)b * 256 + erow) * SP + n * 256 + (((lane & 7) ^ ((lane >> 3) & 7)) * 8);
    }

#define STAGE(CH, BUF) {                                                      \
        char* kl = SH + (BUF) * 32768 + wv * 4096;                            \
        char* vl = SH + 65536 + (BUF) * 32768 + wv * 4096;                    \
        _Pragma("unroll")                                                     \
        for (int i = 0; i < 4; ++i) gll16(ksrcp[i] + (long)(CH) * 16384, kl + i * 1024); \
        _Pragma("unroll")                                                     \
        for (int i = 0; i < 4; ++i) gll16(vsrcp[i] + (CH) * 64, vl + i * 1024);          \
    }

    STAGE(0, 0)
    STAGE(1, 1)
    asm volatile("s_waitcnt vmcnt(8) lgkmcnt(0)" ::: "memory");
    __builtin_amdgcn_s_barrier();

    float mrun = -1e30f, lrun = 0.f;
    f32x4 oacc[16] = {};

    for (int ch = 0; ch < 8; ++ch) {
        const char* KB = SH + (ch & 1) * 32768;
        const char* VB = SH + 65536 + (ch & 1) * 32768;

        // --- energy: E^T[w][q] = mfma(K, Q); 64 keys = 4 w-tiles
        f32x4 eacc[4] = {};
        __builtin_amdgcn_s_setprio(1);
        #pragma unroll
        for (int s = 0; s < 8; ++s) {
            short8 kf[4];
            #pragma unroll
            for (int tt = 0; tt < 4; ++tt)
                kf[tt] = *(const short8*)(KB + (16 * tt + l15) * 512 + (((4 * s + G) ^ (l15 & 7)) * 16));
            #pragma unroll
            for (int tt = 0; tt < 4; ++tt)
                eacc[tt] = __builtin_amdgcn_mfma_f32_16x16x32_bf16(kf[tt], qfrag[s], eacc[tt], 0, 0, 0);
        }
        __builtin_amdgcn_s_setprio(0);

        int w0 = ch * 64;
        f32x4 lm[4], fm[4];
        #pragma unroll
        for (int tt = 0; tt < 4; ++tt) {
            lm[tt] = *(const f32x4*)&lmaskL[w0 + 16 * tt + 4 * G];
            fm[tt] = *(const f32x4*)&fmaskL[w0 + 16 * tt + 4 * G];
        }

        // --- in-lane online softmax (q = l15)
        f32x4 ev[4];
        f32x4 m4;
        #pragma unroll
        for (int tt = 0; tt < 4; ++tt) {
            ev[tt] = eacc[tt] * 0.0625f + lm[tt];
            m4 = tt ? max4(m4, ev[tt]) : ev[tt];
        }
        float cm = fmaxf(fmaxf(m4[0], m4[1]), fmaxf(m4[2], m4[3]));
        cm = fmaxf(cm, __shfl_xor(cm, 16));
        cm = fmaxf(cm, __shfl_xor(cm, 32));
        if (__any(cm > mrun + 8.f)) {
            float mn = fmaxf(mrun, cm);
            float sc = __expf(mrun - mn);
            mrun = mn; lrun *= sc;
            #pragma unroll
            for (int et = 0; et < 16; ++et) oacc[et] *= sc;
        }

        unsigned pc[8];
        float ssum = 0.f;
        #pragma unroll
        for (int tt = 0; tt < 4; ++tt) {
            f32x4 p;
            p[0] = __expf(ev[tt][0] - mrun);
            p[1] = __expf(ev[tt][1] - mrun);
            p[2] = __expf(ev[tt][2] - mrun);
            p[3] = __expf(ev[tt][3] - mrun);
            ssum += (p[0] + p[1]) + (p[2] + p[3]);
            f32x4 pf = p * fm[tt];
            pc[2 * tt]     = pkbf(pf[0], pf[1]);
            pc[2 * tt + 1] = pkbf(pf[2], pf[3]);
        }
        ssum += __shfl_xor(ssum, 16);
        ssum += __shfl_xor(ssum, 32);
        lrun += ssum;

        // --- PV: O^T[e][q] += mfma(V~, P~); sigma-permute makes pc the exact B-fragment
        __builtin_amdgcn_s_setprio(1);
        #pragma unroll
        for (int s = 0; s < 2; ++s) {
            short8 pf = mk8(pc[4 * s], pc[4 * s + 1], pc[4 * s + 2], pc[4 * s + 3]);
            #pragma unroll
            for (int et = 0; et < 16; ++et) {
                short8 vf = *(const short8*)(VB + (16 * et + l15) * 128 + (((4 * s + G) ^ (l15 & 7)) * 16));
                oacc[et] = __builtin_amdgcn_mfma_f32_16x16x32_bf16(vf, pf, oacc[et], 0, 0, 0);
            }
        }
        __builtin_amdgcn_s_setprio(0);

        asm volatile("s_waitcnt lgkmcnt(0)" ::: "memory");
        __builtin_amdgcn_s_barrier();
        if (ch < 6) {
            STAGE(ch + 2, ch & 1)
            asm volatile("s_waitcnt vmcnt(8)" ::: "memory");
        } else if (ch == 6) {
            asm volatile("s_waitcnt vmcnt(0)" ::: "memory");
        }
        __builtin_amdgcn_s_barrier();
    }

    // --- epilogue: 1/l, gelu, pack h fragments in-register
    float linv = 1.f / lrun;
    unsigned hc[32];
    #pragma unroll
    for (int et = 0; et < 16; ++et) {
        f32x4 xv = oacc[et] * linv;
        hc[2 * et]     = pkbf(gelu_t(xv[0]), gelu_t(xv[1]));
        hc[2 * et + 1] = pkbf(gelu_t(xv[2]), gelu_t(xv[3]));
    }
    float ym = fmaskL[128 + qh * 128 + wv * 16 + l15];

    // --- projection: y[o][s] = Wo~ . h~ + bo, Wo LDS-staged through K dbuf
    const unsigned short* wsrcp[4];
    #pragma unroll
    for (int i = 0; i < 4; ++i) {
        int wrow = wv * 8 + i * 2 + (lane >> 5);
        wsrcp[i] = Wo_b + (long)wrow * 256 + (((lane & 31) ^ (wrow & 7)) * 8);
    }
#define WSTAGE(ST, BUF) {                                                     \
        char* wl = SH + (BUF) * 32768 + wv * 4096;                            \
        _Pragma("unroll")                                                     \
        for (int i = 0; i < 4; ++i) gll16(wsrcp[i] + (ST) * 16384, wl + i * 1024); \
    }

    WSTAGE(0, 0)
    WSTAGE(1, 1)
    asm volatile("s_waitcnt vmcnt(4)" ::: "memory");
    __builtin_amdgcn_s_barrier();

    for (int step = 0; step < 8; ++step) {
        const char* WB = SH + (step & 1) * 32768;
        __builtin_amdgcn_s_setprio(1);
        #pragma unroll
        for (int otl = 0; otl < 4; ++otl) {
            f32x4 pacc = {};
            #pragma unroll
            for (int s = 0; s < 8; ++s) {
                short8 wf = *(const short8*)(WB + (16 * otl + l15) * 512 + (((4 * s + G) ^ (l15 & 7)) * 16));
                short8 hs = mk8(hc[4 * s], hc[4 * s + 1], hc[4 * s + 2], hc[4 * s + 3]);
                pacc = __builtin_amdgcn_mfma_f32_16x16x32_bf16(wf, hs, pacc, 0, 0, 0);
            }
            int o0 = step * 64 + 16 * otl + 4 * G;
            f32x4 bo4 = *(const f32x4*)&boL[o0];
            #pragma unroll
            for (int r = 0; r < 4; ++r)
                y[((long)b * Cc + o0 + r) * Ss + sqw + l15] = (pacc[r] + bo4[r]) * ym;
        }
        __builtin_amdgcn_s_setprio(0);
        asm volatile("s_waitcnt lgkmcnt(0)" ::: "memory");
        __builtin_amdgcn_s_barrier();
        if (step < 6) {
            WSTAGE(step + 2, step & 1)
            asm volatile("s_waitcnt vmcnt(4)" ::: "memory");
        } else if (step == 6) {
            asm volatile("s_waitcnt vmcnt(0)" ::: "memory");
        }
        __builtin_amdgcn_s_barrier();
    }
#undef STAGE
#undef WSTAGE
}

extern "C" void kernel_launch(void* const* d_in, const int* in_sizes, int n_in,
                              void* d_out, int out_size, void* d_ws, size_t ws_size,
                              hipStream_t stream)
{
    const float* x1   = (const float*)d_in[0];
    const float* mask = (const float*)d_in[1];
    const float* Wq   = (const float*)d_in[2];
    const float* bq   = (const float*)d_in[3];
    const float* Wk   = (const float*)d_in[4];
    const float* bk   = (const float*)d_in[5];
    const float* Wv   = (const float*)d_in[6];
    const float* bv   = (const float*)d_in[7];
    const float* Wo   = (const float*)d_in[8];
    const float* bo   = (const float*)d_in[9];
    float* y = (float*)d_out;

    // ws layout (bf16): Wqkv_b 786432 | Wo_b 262144 | qT 16777216 | kTp 17301504 | vp 17301504
    // xT (all 4 batches, 33.5MB) lives in d_out (64MB) and is overwritten by y at the end.
    if (ws_size < 52428800u) return;
    char* w = (char*)d_ws;
    unsigned short* Wqkv_b = (unsigned short*)(w);
    unsigned short* Wo_b   = (unsigned short*)(w + 786432);
    unsigned short* qT     = (unsigned short*)(w + 1048576);
    unsigned short* kTp    = (unsigned short*)(w + 17825792);
    unsigned short* vp     = (unsigned short*)(w + 35127296);
    unsigned short* xT4    = (unsigned short*)d_out;

    kpre<<<5888, 256, 0, stream>>>(x1, Wq, Wk, Wv, Wo, Wqkv_b, Wo_b, kTp, vp, xT4);
    kqkv<<<dim3(384, 4), 256, 0, stream>>>(xT4, Wqkv_b, bq, bk, bv, qT, kTp, vp);
    kattn<<<256, 512, 0, stream>>>(qT, kTp, vp, Wo_b, mask, bo, y);
}